// Round 3
// baseline (744.292 us; speedup 1.0000x reference)
//
#include <hip/hip_runtime.h>
#include <math.h>

// ---------------------------------------------------------------------------
// EmbedMatcher: V=200000 D=256 B=2048 F=5 N=64 K=32 DM=512 HID=1024 STEPS=4
// Simplifications (verified vs reference):
//  * GCN mean commutes with linear layer
//  * attn = softmax over ONE column == 1 -> r == support_g (constant)
//  * gates = base + h @ Whh[:, :512]^T + cvec; base/cvec step-invariant
//  * step 0: h_r = 0 -> gates == base
//  * R6: c[:, 512:] dead -> live gates only, big GEMMs N=2048.
//  * R7: persistent LSTM tail — base+3 steps fused into ONE kernel
//    (grid 256 = 1 block/CU, device-scope atomic grid barrier between
//    steps; base/cbuf/qg live in registers; only bf16 h crosses blocks).
// ---------------------------------------------------------------------------

typedef __attribute__((ext_vector_type(8))) short short8;
typedef __attribute__((ext_vector_type(4))) float floatx4;

__device__ inline unsigned short f2bf(float f) {
  union { float f; unsigned int u; } x;
  x.f = f;
  unsigned int r = x.u + 0x7fffu + ((x.u >> 16) & 1u);  // RNE
  return (unsigned short)(r >> 16);
}
__device__ inline float bf2f(unsigned short u) {
  union { unsigned int i; float f; } x;
  x.i = ((unsigned int)u) << 16;
  return x.f;
}
__device__ inline float frcp(float x) { return __builtin_amdgcn_rcpf(x); }
__device__ inline float sigm_f(float x) { return frcp(1.f + __expf(-x)); }
__device__ inline float tanh_f(float x) {
  return 1.f - 2.f * frcp(1.f + __expf(2.f * x));
}

// async global->LDS, 16 B per lane; lane i lands at l + i*16 (wave-uniform l)
#if defined(__has_builtin)
#if __has_builtin(__builtin_amdgcn_global_load_lds)
#define HAVE_GLL 1
#endif
#endif
#ifdef HAVE_GLL
__device__ inline void load_lds16(const void* g, void* l) {
  __builtin_amdgcn_global_load_lds(
      (const __attribute__((address_space(1))) unsigned int*)(uintptr_t)g,
      (__attribute__((address_space(3))) unsigned int*)(unsigned int)(uintptr_t)l,
      16, 0, 0);
}
#else
__device__ inline void load_lds16(const void* g, void* l) {
  const int lane = threadIdx.x & 63;
  *(uint4*)((char*)l + lane * 16) = *(const uint4*)g;
}
#endif

__device__ inline float wave_reduce_sum(float v) {
#pragma unroll
  for (int off = 32; off > 0; off >>= 1) v += __shfl_down(v, off, 64);
  return v;
}

// device-scope grid barrier for a fully-resident grid (1 block/CU).
// bar[0]=arrive counter, bar[1]=generation. Re-zeroed by convert_all each call.
__device__ inline void grid_barrier(unsigned int* bar, unsigned int nbm1) {
  __threadfence();
  __syncthreads();
  if (threadIdx.x == 0) {
    unsigned int g =
        __hip_atomic_load(&bar[1], __ATOMIC_RELAXED, __HIP_MEMORY_SCOPE_AGENT);
    unsigned int a = __hip_atomic_fetch_add(&bar[0], 1u, __ATOMIC_ACQ_REL,
                                            __HIP_MEMORY_SCOPE_AGENT);
    if (a == nbm1) {
      __hip_atomic_store(&bar[0], 0u, __ATOMIC_RELAXED,
                         __HIP_MEMORY_SCOPE_AGENT);
      __hip_atomic_fetch_add(&bar[1], 1u, __ATOMIC_RELEASE,
                             __HIP_MEMORY_SCOPE_AGENT);
    } else {
      while (__hip_atomic_load(&bar[1], __ATOMIC_ACQUIRE,
                               __HIP_MEMORY_SCOPE_AGENT) == g)
        __builtin_amdgcn_s_sleep(2);
    }
  }
  __syncthreads();
}

// ---------------- fused weight convert + permute (one launch) --------------
// Live-gate packing: permuted row r in [0,2048): gate=(r>>4)&3,
// n=((r>>6)<<4)+(r&15) in [0,512). orig = gate*1024 + n.
__global__ __launch_bounds__(256) void convert_all_kernel(
    const float* __restrict__ w_ih, const float* __restrict__ w_hh,
    const float* __restrict__ p1_w, const float* __restrict__ p2_w,
    const float* __restrict__ gcn_w, const float* __restrict__ b_ih,
    const float* __restrict__ b_hh, unsigned short* __restrict__ wihb,
    unsigned short* __restrict__ whhb, unsigned short* __restrict__ p1b,
    unsigned short* __restrict__ p2b, unsigned short* __restrict__ gcnb,
    float* __restrict__ bcomb, unsigned int* __restrict__ bar) {
  const int p = blockIdx.x * 256 + threadIdx.x;
  if (p == 0) { bar[0] = 0u; bar[1] = 0u; }
  if (p < 262144) {
    const int e = p * 4, r = e >> 9, c = e & 511;
    const int orig = ((r >> 4) & 3) * 1024 + ((r >> 6) << 4) + (r & 15);
    float4 v = *(const float4*)(w_ih + (size_t)orig * 512 + c);
    *(ushort4*)(wihb + (size_t)r * 512 + c) =
        make_ushort4(f2bf(v.x), f2bf(v.y), f2bf(v.z), f2bf(v.w));
  } else if (p < 524288) {
    const int e = (p - 262144) * 4, r = e >> 9, c = e & 511;
    const int orig = ((r >> 4) & 3) * 1024 + ((r >> 6) << 4) + (r & 15);
    float4 v = *(const float4*)(w_hh + (size_t)orig * 1024 + c);
    *(ushort4*)(whhb + (size_t)r * 512 + c) =
        make_ushort4(f2bf(v.x), f2bf(v.y), f2bf(v.z), f2bf(v.w));
  } else if (p < 655360) {
    const int e = (p - 524288) * 4;
    float4 v = *(const float4*)(p1_w + e);
    *(ushort4*)(p1b + e) =
        make_ushort4(f2bf(v.x), f2bf(v.y), f2bf(v.z), f2bf(v.w));
  } else if (p < 786432) {
    const int e = (p - 655360) * 4;
    float4 v = *(const float4*)(p2_w + e);
    *(ushort4*)(p2b + e) =
        make_ushort4(f2bf(v.x), f2bf(v.y), f2bf(v.z), f2bf(v.w));
  } else if (p < 819200) {
    const int e = (p - 786432) * 4;
    float4 v = *(const float4*)(gcn_w + e);
    *(ushort4*)(gcnb + e) =
        make_ushort4(f2bf(v.x), f2bf(v.y), f2bf(v.z), f2bf(v.w));
  } else if (p < 819712) {
    const int c = (p - 819200) * 4;
    const int orig = ((c >> 4) & 3) * 1024 + ((c >> 6) << 4) + (c & 15);
    float4 a = *(const float4*)(b_ih + orig);
    float4 b = *(const float4*)(b_hh + orig);
    *(float4*)(bcomb + c) =
        make_float4(a.x + b.x, a.y + b.y, a.z + b.z, a.w + b.w);
  }
}

// ---------------- neighbor encoder v5: reg-cached ent rows -----------------
__global__ __launch_bounds__(256) void neighbor_kernel(
    const int* __restrict__ query, const int* __restrict__ support,
    const int* __restrict__ qlc, const int* __restrict__ qrc,
    const int* __restrict__ slc, const int* __restrict__ src_,
    const float* __restrict__ emb, unsigned short* __restrict__ mc,
    int B, int F) {
  const int r = blockIdx.x;
  const int tid = threadIdx.x;
  const int* conn;
  int id;
  if (r < B) {
    conn = qlc + (size_t)r * 128; id = query[2 * r];
  } else if (r < 2 * B) {
    int b = r - B; conn = qrc + (size_t)b * 128; id = query[2 * b + 1];
  } else if (r < 2 * B + F) {
    int f = r - 2 * B; conn = slc + (size_t)f * 128; id = support[2 * f];
  } else {
    int f = r - 2 * B - F; conn = src_ + (size_t)f * 128; id = support[2 * f + 1];
  }

  __shared__ __align__(16) float cent[256];
  __shared__ __align__(16) float entpart[4 * 256];
  __shared__ float sims[64];
  __shared__ int rel_ids[64];
  __shared__ int ent_ids[64];
  __shared__ short list[32];
  __shared__ float red[4];
  __shared__ float cnorm_s;
  __shared__ unsigned long long selmask_s;

  if (tid < 64) {
    rel_ids[tid] = conn[2 * tid];
    ent_ids[tid] = conn[2 * tid + 1];
  }
  float cv = emb[(size_t)id * 256 + tid];
  cent[tid] = cv;
  float sq = wave_reduce_sum(cv * cv);
  if ((tid & 63) == 0) red[tid >> 6] = sq;
  __syncthreads();
  if (tid == 0) cnorm_s = sqrtf(red[0] + red[1] + red[2] + red[3]);
  __syncthreads();
  const float cn = cnorm_s;

  const int wave = tid >> 6, lane = tid & 63;
  const float4 cv4 = *(const float4*)(cent + lane * 4);
  uint2 ec[16];  // bf16x4-packed cache of this wave's 16 ent rows (lane slice)
#pragma unroll
  for (int t = 0; t < 16; ++t) {
    const int n = wave + 4 * t;
    const float* er = emb + (size_t)ent_ids[n] * 256;
    float4 e = *(const float4*)(er + lane * 4);
    ec[t].x = (unsigned)f2bf(e.x) | ((unsigned)f2bf(e.y) << 16);
    ec[t].y = (unsigned)f2bf(e.z) | ((unsigned)f2bf(e.w) << 16);
    float d = e.x * cv4.x + e.y * cv4.y + e.z * cv4.z + e.w * cv4.w;
    float s2 = e.x * e.x + e.y * e.y + e.z * e.z + e.w * e.w;
#pragma unroll
    for (int off = 32; off > 0; off >>= 1) {
      d += __shfl_down(d, off, 64);
      s2 += __shfl_down(s2, off, 64);
    }
    if (lane == 0) sims[n] = d / fmaxf(cn * sqrtf(s2), 1e-8f);
  }
  __syncthreads();

  // top-K=32, stable tie-break (lower index first) == lax.top_k (wave 0 only)
  if (wave == 0) {
    float my = sims[lane];
    int rank = 0;
#pragma unroll 8
    for (int j = 0; j < 64; ++j) {
      float sj = sims[j];
      rank += (sj > my) || (sj == my && j < lane);
    }
    if (rank < 32) list[rank] = (short)lane;
    unsigned long long m = __ballot(rank < 32);
    if (lane == 0) selmask_s = m;
  }
  __syncthreads();

  // selected-ent partial sums from register cache
  const unsigned long long selm = selmask_s;
  float4 pa = make_float4(0.f, 0.f, 0.f, 0.f);
#pragma unroll
  for (int t = 0; t < 16; ++t) {
    const int n = wave + 4 * t;
    if ((selm >> n) & 1ull) {
      pa.x += bf2f((unsigned short)(ec[t].x & 0xffff));
      pa.y += bf2f((unsigned short)(ec[t].x >> 16));
      pa.z += bf2f((unsigned short)(ec[t].y & 0xffff));
      pa.w += bf2f((unsigned short)(ec[t].y >> 16));
    }
  }
  *(float4*)&entpart[wave * 256 + lane * 4] = pa;
  __syncthreads();

  // rel gather (selected 32 rows) + combine ent partials
  float accR = 0.f;
#pragma unroll 2
  for (int k = 0; k < 32; k += 4) {
    const int n0 = list[k], n1 = list[k + 1], n2 = list[k + 2], n3 = list[k + 3];
    const float* p0 = emb + (size_t)rel_ids[n0] * 256;
    const float* p1 = emb + (size_t)rel_ids[n1] * 256;
    const float* p2 = emb + (size_t)rel_ids[n2] * 256;
    const float* p3 = emb + (size_t)rel_ids[n3] * 256;
    accR += (p0[tid] + p1[tid]) + (p2[tid] + p3[tid]);
  }
  const float accE = entpart[tid] + entpart[256 + tid] + entpart[512 + tid] +
                     entpart[768 + tid];
  mc[(size_t)r * 512 + tid] = f2bf(accR * (1.f / 32.f));
  mc[(size_t)r * 512 + 256 + tid] = f2bf(accE * (1.f / 32.f));
}

// ------------- persistent LSTM tail: base GEMM + 3 steps, grid-synced ------
// grid MUST be (16,16) = 256 blocks (1/CU, fully resident).
// A=qgb/hb (2048x512 bf16), B=wihb/whhb (2048x512 bf16), K=512.
// base(+bcomb), cbuf, qg tiles live in registers across steps.
__global__ __launch_bounds__(256, 1) void lstm_tail_kernel(
    const unsigned short* __restrict__ qgb,
    const unsigned short* __restrict__ wihb,
    const unsigned short* __restrict__ whhb,
    const float* __restrict__ bcomb, const float* __restrict__ cvec,
    const float* __restrict__ qg, unsigned short* __restrict__ hb0,
    unsigned short* __restrict__ hb1, float* __restrict__ hout,
    unsigned int* __restrict__ bar) {
  __shared__ __align__(16) unsigned short As[128 * 32];
  __shared__ __align__(16) unsigned short Bs[128 * 32];
  const int tid = threadIdx.x;
  const int wid = tid >> 6, lane = tid & 63;
  const int quad = lane >> 4, l16 = lane & 15;
  const int wr = (wid >> 1) * 64, wc = (wid & 1) * 64;
  const int row0 = blockIdx.y * 128, col0 = blockIdx.x * 128;
  const unsigned int nbm1 = gridDim.x * gridDim.y - 1;

  const int rl = lane >> 2;
  const int q = (lane & 3) ^ ((lane >> 3) & 3);
  unsigned short* lA0 = &As[(wid * 32) * 32];
  unsigned short* lA1 = &As[(wid * 32 + 16) * 32];
  unsigned short* lB0 = &Bs[(wid * 32) * 32];
  unsigned short* lB1 = &Bs[(wid * 32 + 16) * 32];
  const int pq = quad ^ ((l16 >> 1) & 3);
  const unsigned short* fA = &As[(wr + l16) * 32 + pq * 8];
  const unsigned short* fB = &Bs[(wc + l16) * 32 + pq * 8];

  // per-thread gate index (same for all j; j IS the gate i,f,g,o)
  const int n = (((col0 + wc) >> 6) << 4) + l16;
  float bcv[4], cvv[4];
#pragma unroll
  for (int j = 0; j < 4; ++j) {
    const int col = col0 + wc + j * 16 + l16;
    bcv[j] = bcomb[col];
    cvv[j] = cvec[col];
  }
  float qv[4][4];
#pragma unroll
  for (int i = 0; i < 4; ++i)
#pragma unroll
    for (int r = 0; r < 4; ++r)
      qv[i][r] = qg[(size_t)(row0 + wr + i * 16 + quad * 4 + r) * 512 + n];

  float bg[4][4][4];  // base gates (incl. bcomb), persistent
  float cb[4][4];     // cell state, persistent

  for (int s = 0; s < 4; ++s) {
    const unsigned short* Ab = (s == 0) ? qgb : ((s == 2) ? hb1 : hb0);
    const unsigned short* Bb = (s == 0) ? wihb : whhb;
    const unsigned short* Ap0 =
        Ab + (size_t)(row0 + wid * 32 + rl) * 512 + q * 8;
    const unsigned short* Ap1 = Ap0 + (size_t)16 * 512;
    const unsigned short* Bp0 =
        Bb + (size_t)(col0 + wid * 32 + rl) * 512 + q * 8;
    const unsigned short* Bp1 = Bp0 + (size_t)16 * 512;

    floatx4 acc[4][4];
#pragma unroll
    for (int i = 0; i < 4; ++i)
#pragma unroll
      for (int j = 0; j < 4; ++j) {
        floatx4 z = {0.f, 0.f, 0.f, 0.f};
        acc[i][j] = z;
      }

    for (int k0 = 0; k0 < 512; k0 += 32) {
      load_lds16(Ap0, lA0);
      load_lds16(Ap1, lA1);
      load_lds16(Bp0, lB0);
      load_lds16(Bp1, lB1);
      Ap0 += 32; Ap1 += 32; Bp0 += 32; Bp1 += 32;
      __syncthreads();

      short8 af[4], bfr[4];
#pragma unroll
      for (int i = 0; i < 4; ++i) af[i] = *(const short8*)(fA + i * 16 * 32);
#pragma unroll
      for (int j = 0; j < 4; ++j) bfr[j] = *(const short8*)(fB + j * 16 * 32);
#pragma unroll
      for (int i = 0; i < 4; ++i)
#pragma unroll
        for (int j = 0; j < 4; ++j)
          acc[i][j] = __builtin_amdgcn_mfma_f32_16x16x32_bf16(
              af[i], bfr[j], acc[i][j], 0, 0, 0);
      __syncthreads();
    }

    if (s == 0) {
#pragma unroll
      for (int i = 0; i < 4; ++i)
#pragma unroll
        for (int r = 0; r < 4; ++r) {
          const int row = row0 + wr + i * 16 + quad * 4 + r;
#pragma unroll
          for (int j = 0; j < 4; ++j) bg[i][j][r] = acc[i][j][r] + bcv[j];
          // cell step 0: cold = 0
          const float cn = sigm_f(bg[i][0][r]) * tanh_f(bg[i][2][r]);
          cb[i][r] = cn;
          const float hv = qv[i][r] + sigm_f(bg[i][3][r]) * tanh_f(cn);
          hb0[(size_t)row * 512 + n] = f2bf(hv);
        }
    } else {
#pragma unroll
      for (int i = 0; i < 4; ++i)
#pragma unroll
        for (int r = 0; r < 4; ++r) {
          const int row = row0 + wr + i * 16 + quad * 4 + r;
          float v0 = acc[i][0][r] + bg[i][0][r] + cvv[0];
          float v1 = acc[i][1][r] + bg[i][1][r] + cvv[1];
          float v2 = acc[i][2][r] + bg[i][2][r] + cvv[2];
          float v3 = acc[i][3][r] + bg[i][3][r] + cvv[3];
          const float cn = sigm_f(v1) * cb[i][r] + sigm_f(v0) * tanh_f(v2);
          cb[i][r] = cn;
          const float hv = qv[i][r] + sigm_f(v3) * tanh_f(cn);
          if (s == 1) hb1[(size_t)row * 512 + n] = f2bf(hv);
          else if (s == 2) hb0[(size_t)row * 512 + n] = f2bf(hv);
          else hout[(size_t)row * 512 + n] = hv;
        }
    }
    if (s < 3) grid_barrier(bar, nbm1);
  }
}

// ------------- bf16 MFMA GEMM_NT 64x64, global_load_lds staging ------------
// N % 64 == 0, K % 32 == 0, M arbitrary (A rows clamped; writes guarded).
// snptr != null => GCN remap epilogue (scatter rows to qn/qnb/sn).
__global__ __launch_bounds__(256) void gemm64_kernel(
    const unsigned short* __restrict__ A, int lda,
    const unsigned short* __restrict__ Bm, int ldb,
    float* __restrict__ C, unsigned short* __restrict__ Cbf,
    int M, int N, int K,
    const float* __restrict__ bias1, const float* __restrict__ bias2,
    const float* __restrict__ addmat, int act, int rB, int rF,
    float* __restrict__ snptr) {
  __shared__ __align__(16) unsigned short As[64 * 32];
  __shared__ __align__(16) unsigned short Bs[64 * 32];
  const int tid = threadIdx.x;
  const int wid = tid >> 6, lane = tid & 63;
  const int quad = lane >> 4, l16 = lane & 15;
  const int wr = (wid >> 1) * 32, wc = (wid & 1) * 32;
  const int row0 = blockIdx.y * 64, col0 = blockIdx.x * 64;

  // staging: waves 0,1 -> A rows [0,32)/[32,64); waves 2,3 -> B likewise
  const int half = wid >> 1;       // 0=A 1=B
  const int grp = (wid & 1) * 32;
  const int rl = lane >> 2;
  const int q = (lane & 3) ^ ((lane >> 3) & 3);
  const unsigned short* src = half ? Bm : A;
  const int lds = half ? ldb : lda;
  const int r0s = half ? col0 : row0;
  int rg0 = r0s + grp + rl;
  int rg1 = rg0 + 16;
  if (!half) {  // clamp A rows (data valid; epilogue guards writes)
    rg0 = min(rg0, M - 1);
    rg1 = min(rg1, M - 1);
  }
  const unsigned short* P0 = src + (size_t)rg0 * lds + q * 8;
  const unsigned short* P1 = src + (size_t)rg1 * lds + q * 8;
  unsigned short* L0 = (half ? Bs : As) + grp * 32;
  unsigned short* L1 = L0 + 16 * 32;

  const int pq = quad ^ ((l16 >> 1) & 3);
  const unsigned short* fA = &As[(wr + l16) * 32 + pq * 8];
  const unsigned short* fB = &Bs[(wc + l16) * 32 + pq * 8];

  floatx4 acc[2][2];
#pragma unroll
  for (int i = 0; i < 2; ++i)
#pragma unroll
    for (int j = 0; j < 2; ++j) {
      floatx4 z = {0.f, 0.f, 0.f, 0.f};
      acc[i][j] = z;
    }

  for (int k0 = 0; k0 < K; k0 += 32) {
    load_lds16(P0, L0);
    load_lds16(P1, L1);
    P0 += 32; P1 += 32;
    __syncthreads();

    short8 af[2], bfr[2];
#pragma unroll
    for (int i = 0; i < 2; ++i) af[i] = *(const short8*)(fA + i * 16 * 32);
#pragma unroll
    for (int j = 0; j < 2; ++j) bfr[j] = *(const short8*)(fB + j * 16 * 32);
#pragma unroll
    for (int i = 0; i < 2; ++i)
#pragma unroll
      for (int j = 0; j < 2; ++j)
        acc[i][j] = __builtin_amdgcn_mfma_f32_16x16x32_bf16(af[i], bfr[j],
                                                            acc[i][j], 0, 0, 0);
    __syncthreads();
  }

#pragma unroll
  for (int i = 0; i < 2; ++i) {
#pragma unroll
    for (int r = 0; r < 4; ++r) {
      const int row = row0 + wr + i * 16 + quad * 4 + r;
      if (row >= M) continue;
#pragma unroll
      for (int j = 0; j < 2; ++j) {
        const int col = col0 + wc + j * 16 + l16;
        float v = acc[i][j][r];
        if (bias1) v += bias1[col];
        if (bias2) v += bias2[col];
        if (addmat) v += addmat[(size_t)row * N + col];
        if (act == 1) v = tanh_f(v);
        else if (act == 2) v = fmaxf(v, 0.f);
        if (snptr) {  // GCN remap: row -> {qn | qn+256 | sn | sn+256}
          if (row < rB) {
            C[(size_t)row * 512 + col] = v;
            Cbf[(size_t)row * 512 + col] = f2bf(v);
          } else if (row < 2 * rB) {
            C[(size_t)(row - rB) * 512 + 256 + col] = v;
            Cbf[(size_t)(row - rB) * 512 + 256 + col] = f2bf(v);
          } else if (row < 2 * rB + rF) {
            snptr[(size_t)(row - 2 * rB) * 512 + col] = v;
          } else {
            snptr[(size_t)(row - 2 * rB - rF) * 512 + 256 + col] = v;
          }
        } else {
          if (C) C[(size_t)row * N + col] = v;
          if (Cbf) Cbf[(size_t)row * N + col] = f2bf(v);
        }
      }
    }
  }
}

// ------------- fp32 GEMM_NT (tiny M=F support path) ------------------------
__global__ __launch_bounds__(256) void gemm_nt_kernel(
    const float* __restrict__ A, int lda, const float* __restrict__ B, int ldb,
    float* __restrict__ C, int M, int N, int K,
    const float* __restrict__ bias1, const float* __restrict__ bias2,
    const float* __restrict__ addmat, int act) {
  __shared__ float As[16][65];
  __shared__ float Bs[16][65];
  const int tid = threadIdx.x;
  const int col0 = blockIdx.x * 64;
  const int row0 = blockIdx.y * 64;
  const int tx = tid & 15, ty = tid >> 4;
  const int lr = tid >> 2, lk = (tid & 3) << 2;

  float acc[4][4];
#pragma unroll
  for (int i = 0; i < 4; ++i)
#pragma unroll
    for (int j = 0; j < 4; ++j) acc[i][j] = 0.f;

  const int ar = row0 + lr;
  const bool avalid = ar < M;
  const float* Aptr = A + (size_t)ar * lda + lk;
  const float* Bptr = B + (size_t)(col0 + lr) * ldb + lk;

  for (int k0 = 0; k0 < K; k0 += 16) {
    float4 av = make_float4(0.f, 0.f, 0.f, 0.f);
    if (avalid) av = *(const float4*)(Aptr + k0);
    float4 bv = *(const float4*)(Bptr + k0);
    As[lk + 0][lr] = av.x; As[lk + 1][lr] = av.y;
    As[lk + 2][lr] = av.z; As[lk + 3][lr] = av.w;
    Bs[lk + 0][lr] = bv.x; Bs[lk + 1][lr] = bv.y;
    Bs[lk + 2][lr] = bv.z; Bs[lk + 3][lr] = bv.w;
    __syncthreads();
#pragma unroll
    for (int k = 0; k < 16; ++k) {
      float a0 = As[k][ty * 4 + 0], a1 = As[k][ty * 4 + 1];
      float a2 = As[k][ty * 4 + 2], a3 = As[k][ty * 4 + 3];
      float b0 = Bs[k][tx * 4 + 0], b1 = Bs[k][tx * 4 + 1];
      float b2 = Bs[k][tx * 4 + 2], b3 = Bs[k][tx * 4 + 3];
      acc[0][0] += a0 * b0; acc[0][1] += a0 * b1; acc[0][2] += a0 * b2; acc[0][3] += a0 * b3;
      acc[1][0] += a1 * b0; acc[1][1] += a1 * b1; acc[1][2] += a1 * b2; acc[1][3] += a1 * b3;
      acc[2][0] += a2 * b0; acc[2][1] += a2 * b1; acc[2][2] += a2 * b2; acc[2][3] += a2 * b3;
      acc[3][0] += a3 * b0; acc[3][1] += a3 * b1; acc[3][2] += a3 * b2; acc[3][3] += a3 * b3;
    }
    __syncthreads();
  }

#pragma unroll
  for (int i = 0; i < 4; ++i) {
    const int r = row0 + ty * 4 + i;
    if (r >= M) continue;
#pragma unroll
    for (int j = 0; j < 4; ++j) {
      const int c = col0 + tx * 4 + j;
      float v = acc[i][j];
      if (bias1) v += bias1[c];
      if (bias2) v += bias2[c];
      if (addmat) v += addmat[(size_t)r * N + c];
      if (act == 1) v = tanhf(v);
      else if (act == 2) v = fmaxf(v, 0.f);
      C[(size_t)r * N + c] = v;
    }
  }
}

// ------------- LayerNorm rows of 512; optional bf16 copy (queries) ---------
__global__ __launch_bounds__(256) void ln_kernel(
    const float* __restrict__ X, float* __restrict__ Y,
    unsigned short* __restrict__ Ybf,
    const float* __restrict__ g, const float* __restrict__ bta) {
  const int r = blockIdx.x;
  const int tid = threadIdx.x;
  const float* x = X + (size_t)r * 512;
  float x0 = x[tid], x1 = x[tid + 256];
  __shared__ float red[4];
  float s = wave_reduce_sum(x0 + x1);
  if ((tid & 63) == 0) red[tid >> 6] = s;
  __syncthreads();
  const float mean = (red[0] + red[1] + red[2] + red[3]) * (1.f / 512.f);
  __syncthreads();
  const float d0 = x0 - mean, d1 = x1 - mean;
  float v = wave_reduce_sum(d0 * d0 + d1 * d1);
  if ((tid & 63) == 0) red[tid >> 6] = v;
  __syncthreads();
  const float var = (red[0] + red[1] + red[2] + red[3]) * (1.f / 512.f);
  const float inv = 1.f / sqrtf(var + 1e-5f);
  const float y0 = d0 * inv * g[tid] + bta[tid];
  const float y1 = d1 * inv * g[tid + 256] + bta[tid + 256];
  float* y = Y + (size_t)r * 512;
  y[tid] = y0;
  y[tid + 256] = y1;
  if (Ybf) {
    Ybf[(size_t)r * 512 + tid] = f2bf(y0);
    Ybf[(size_t)r * 512 + tid + 256] = f2bf(y1);
  }
}

// ------------- support LN (F rows) + mean -> sg, single block --------------
__global__ __launch_bounds__(256) void lns_kernel(
    const float* __restrict__ X, const float* __restrict__ g,
    const float* __restrict__ bta, float* __restrict__ sg, int F) {
  const int tid = threadIdx.x;
  __shared__ float red[4];
  float a0 = 0.f, a1 = 0.f;
  for (int f = 0; f < F; ++f) {
    const float* x = X + (size_t)f * 512;
    const float x0 = x[tid], x1 = x[tid + 256];
    float s = wave_reduce_sum(x0 + x1);
    if ((tid & 63) == 0) red[tid >> 6] = s;
    __syncthreads();
    const float mean = (red[0] + red[1] + red[2] + red[3]) * (1.f / 512.f);
    __syncthreads();
    const float d0 = x0 - mean, d1 = x1 - mean;
    float v = wave_reduce_sum(d0 * d0 + d1 * d1);
    if ((tid & 63) == 0) red[tid >> 6] = v;
    __syncthreads();
    const float var = (red[0] + red[1] + red[2] + red[3]) * (1.f / 512.f);
    const float inv = 1.f / sqrtf(var + 1e-5f);
    a0 += d0 * inv * g[tid] + bta[tid];
    a1 += d1 * inv * g[tid + 256] + bta[tid + 256];
    __syncthreads();
  }
  sg[tid] = a0 / (float)F;
  sg[tid + 256] = a1 / (float)F;
}

// ------------- cvec[jp] = sum_d sg[d] * w_hh[orig(jp), 512+d] (permuted) ---
// live gates only: jp in [0,2048)
__global__ __launch_bounds__(256) void cvec_kernel(
    const float* __restrict__ whh, const float* __restrict__ sg,
    float* __restrict__ cv) {
  const int wave = threadIdx.x >> 6, lane = threadIdx.x & 63;
  const int jp = blockIdx.x * 4 + wave;
  const int orig = ((jp >> 4) & 3) * 1024 + ((jp >> 6) << 4) + (jp & 15);
  const float* wr = whh + (size_t)orig * 1024 + 512;
  float s = 0.f;
#pragma unroll
  for (int d = lane; d < 512; d += 64) s += wr[d] * sg[d];
  s = wave_reduce_sum(s);
  if (lane == 0) cv[jp] = s;
}

// ------------- out[b] = cosine(h[b], sg) -----------------------------------
__global__ __launch_bounds__(256) void final_kernel(
    const float* __restrict__ h, const float* __restrict__ sg,
    float* __restrict__ out) {
  const int b = blockIdx.x, tid = threadIdx.x;
  const float* hr = h + (size_t)b * 512;
  const float h0 = hr[tid], h1 = hr[tid + 256];
  const float s0 = sg[tid], s1 = sg[tid + 256];
  float d = h0 * s0 + h1 * s1;
  float hh = h0 * h0 + h1 * h1;
  float ssq = s0 * s0 + s1 * s1;
  __shared__ float red[3][4];
  d = wave_reduce_sum(d);
  hh = wave_reduce_sum(hh);
  ssq = wave_reduce_sum(ssq);
  if ((tid & 63) == 0) {
    red[0][tid >> 6] = d; red[1][tid >> 6] = hh; red[2][tid >> 6] = ssq;
  }
  __syncthreads();
  if (tid == 0) {
    const float D = red[0][0] + red[0][1] + red[0][2] + red[0][3];
    const float H = red[1][0] + red[1][1] + red[1][2] + red[1][3];
    const float S = red[2][0] + red[2][1] + red[2][2] + red[2][3];
    out[b] = D / (fmaxf(sqrtf(H), 1e-12f) * fmaxf(sqrtf(S), 1e-12f));
  }
}

extern "C" void kernel_launch(void* const* d_in, const int* in_sizes, int n_in,
                              void* d_out, int out_size, void* d_ws, size_t ws_size,
                              hipStream_t stream) {
  const int* query = (const int*)d_in[0];
  const int* support = (const int*)d_in[1];
  const int* qlc = (const int*)d_in[2];
  const int* qrc = (const int*)d_in[4];
  const int* slc = (const int*)d_in[6];
  const int* src_ = (const int*)d_in[8];
  const float* emb = (const float*)d_in[10];
  const float* gcn_w = (const float*)d_in[11];
  const float* gcn_wb = (const float*)d_in[12];
  const float* gcn_b = (const float*)d_in[13];
  const float* p1_w = (const float*)d_in[14];
  const float* p1_b = (const float*)d_in[15];
  const float* p2_w = (const float*)d_in[16];
  const float* p2_b = (const float*)d_in[17];
  const float* ln_g = (const float*)d_in[18];
  const float* ln_b = (const float*)d_in[19];
  const float* w_ih = (const float*)d_in[20];
  const float* w_hh = (const float*)d_in[21];
  const float* b_ih = (const float*)d_in[22];
  const float* b_hh = (const float*)d_in[23];
  float* out = (float*)d_out;

  const int B = in_sizes[0] / 2;   // 2048
  const int F = in_sizes[1] / 2;   // 5
  const int NR = 2 * B + 2 * F;    // 4106

  char* Wb = (char*)d_ws;
  size_t off = 0;
  auto alloc = [&](size_t bytes) {
    size_t o = off;
    off += (bytes + 255) & ~(size_t)255;
    return o;
  };
  const size_t mc_o   = alloc((size_t)NR * 512 * 2);
  const size_t qn_o   = alloc((size_t)B * 512 * 4);
  const size_t qnb_o  = alloc((size_t)B * 512 * 2);
  const size_t hqb_o  = alloc((size_t)B * 1024 * 2);
  const size_t oq_o   = alloc((size_t)B * 512 * 4);
  const size_t qg_o   = alloc((size_t)B * 512 * 4);
  const size_t qgb_o  = alloc((size_t)B * 512 * 2);
  const size_t h_o    = alloc((size_t)B * 512 * 4);
  const size_t hb0_o  = alloc((size_t)B * 512 * 2);
  const size_t hb1_o  = alloc((size_t)B * 512 * 2);
  const size_t wihb_o = alloc((size_t)2048 * 512 * 2);
  const size_t whhb_o = alloc((size_t)2048 * 512 * 2);
  const size_t p1b_o  = alloc((size_t)1024 * 512 * 2);
  const size_t p2b_o  = alloc((size_t)512 * 1024 * 2);
  const size_t gcnb_o = alloc((size_t)256 * 512 * 2);
  const size_t bcomb_o= alloc(2048 * 4);
  const size_t sn_o   = alloc((size_t)F * 512 * 4);
  const size_t hs_o   = alloc((size_t)F * 1024 * 4);
  const size_t oss_o  = alloc((size_t)F * 512 * 4);
  const size_t sg_o   = alloc(512 * 4);
  const size_t cvec_o = alloc(2048 * 4);
  const size_t bar_o  = alloc(256);

  auto F32 = [&](size_t o) { return (float*)(Wb + o); };
  auto BF = [&](size_t o) { return (unsigned short*)(Wb + o); };

  // 0. weight converts + gate permutation (live gates only) + combined bias
  //    + grid-barrier counter re-init (workspace is poisoned between calls)
  convert_all_kernel<<<3202, 256, 0, stream>>>(
      w_ih, w_hh, p1_w, p2_w, gcn_w, b_ih, b_hh, BF(wihb_o), BF(whhb_o),
      BF(p1b_o), BF(p2b_o), BF(gcnb_o), F32(bcomb_o),
      (unsigned int*)(Wb + bar_o));

  // 1. neighbor encoder -> mc (NR x 512, bf16)
  neighbor_kernel<<<NR, 256, 0, stream>>>(query, support, qlc, qrc, slc, src_,
                                          emb, BF(mc_o), B, F);
  // 2. GCN + remap fused
  {
    dim3 g(256 / 64, (NR + 63) / 64);
    gemm64_kernel<<<g, 256, 0, stream>>>(BF(mc_o), 512, BF(gcnb_o), 512,
                                         F32(qn_o), BF(qnb_o), NR, 256, 512,
                                         gcn_wb, gcn_b, nullptr, 1, B, F,
                                         F32(sn_o));
  }
  // 3-4. support_encoder(queries)
  {
    dim3 g(1024 / 64, B / 64);
    gemm64_kernel<<<g, 256, 0, stream>>>(BF(qnb_o), 512, BF(p1b_o), 512,
                                         nullptr, BF(hqb_o), B, 1024, 512,
                                         p1_b, nullptr, nullptr, 2, 0, 0,
                                         nullptr);
  }
  {
    dim3 g(512 / 64, B / 64);
    gemm64_kernel<<<g, 256, 0, stream>>>(BF(hqb_o), 1024, BF(p2b_o), 1024,
                                         F32(oq_o), nullptr, B, 512, 1024,
                                         p2_b, nullptr, F32(qn_o), 0, 0, 0,
                                         nullptr);
  }
  // 5-6. support_encoder(supports): fp32 (M=5)
  {
    dim3 g(1024 / 64, 1);
    gemm_nt_kernel<<<g, 256, 0, stream>>>(F32(sn_o), 512, p1_w, 512, F32(hs_o),
                                          F, 1024, 512, p1_b, nullptr, nullptr,
                                          2);
  }
  {
    dim3 g(512 / 64, 1);
    gemm_nt_kernel<<<g, 256, 0, stream>>>(F32(hs_o), 1024, p2_w, 1024,
                                          F32(oss_o), F, 512, 1024, p2_b,
                                          nullptr, F32(sn_o), 0);
  }
  // 7. support LN + mean -> sg (one block)
  lns_kernel<<<1, 256, 0, stream>>>(F32(oss_o), ln_g, ln_b, F32(sg_o), F);
  // 8. LN queries -> qg f32 + bf16
  ln_kernel<<<B, 256, 0, stream>>>(F32(oq_o), F32(qg_o), BF(qgb_o), ln_g, ln_b);
  // 9. cvec (gate-permuted, live gates only)
  cvec_kernel<<<512, 256, 0, stream>>>(w_hh, F32(sg_o), F32(cvec_o));
  // 10. persistent LSTM tail: base + 3 steps, grid-synced (256 blocks = 1/CU)
  {
    dim3 g(2048 / 128, B / 128);  // (16,16)
    lstm_tail_kernel<<<g, 256, 0, stream>>>(
        BF(qgb_o), BF(wihb_o), BF(whhb_o), F32(bcomb_o), F32(cvec_o),
        F32(qg_o), BF(hb0_o), BF(hb1_o), F32(h_o),
        (unsigned int*)(Wb + bar_o));
  }
  // 11. output
  final_kernel<<<B, 256, 0, stream>>>(F32(h_o), F32(sg_o), out);
}

// Round 4
// 616.892 us; speedup vs baseline: 1.2065x; 1.2065x over previous
//
#include <hip/hip_runtime.h>
#include <math.h>

// ---------------------------------------------------------------------------
// EmbedMatcher: V=200000 D=256 B=2048 F=5 N=64 K=32 DM=512 HID=1024 STEPS=4
// Simplifications (verified vs reference):
//  * GCN mean commutes with linear layer
//  * attn = softmax over ONE column == 1 -> r == support_g (constant)
//  * gates = base + h @ Whh[:, :512]^T + cvec; base/cvec step-invariant
//  * step 0: h_r = 0 -> gates == base
//  * R6: c[:, 512:] dead -> live gates only, big GEMMs N=2048.
//  * R8: R7 persistent tail REVERTED (1 wave/SIMD latency-bound, 195us).
//    New lstm_step_kernel: 64x64 tile (grid 32x32 = 4 blocks/CU), wave =
//    16 rows x 64 cols (all 4 gates per lane), double-buffered LDS with
//    ONE barrier per K-step (prefetch k+1 under compute of k).
// ---------------------------------------------------------------------------

typedef __attribute__((ext_vector_type(8))) short short8;
typedef __attribute__((ext_vector_type(4))) float floatx4;

__device__ inline unsigned short f2bf(float f) {
  union { float f; unsigned int u; } x;
  x.f = f;
  unsigned int r = x.u + 0x7fffu + ((x.u >> 16) & 1u);  // RNE
  return (unsigned short)(r >> 16);
}
__device__ inline float bf2f(unsigned short u) {
  union { unsigned int i; float f; } x;
  x.i = ((unsigned int)u) << 16;
  return x.f;
}
__device__ inline float frcp(float x) { return __builtin_amdgcn_rcpf(x); }
__device__ inline float sigm_f(float x) { return frcp(1.f + __expf(-x)); }
__device__ inline float tanh_f(float x) {
  return 1.f - 2.f * frcp(1.f + __expf(2.f * x));
}

// async global->LDS, 16 B per lane; lane i lands at l + i*16 (wave-uniform l)
#if defined(__has_builtin)
#if __has_builtin(__builtin_amdgcn_global_load_lds)
#define HAVE_GLL 1
#endif
#endif
#ifdef HAVE_GLL
__device__ inline void load_lds16(const void* g, void* l) {
  __builtin_amdgcn_global_load_lds(
      (const __attribute__((address_space(1))) unsigned int*)(uintptr_t)g,
      (__attribute__((address_space(3))) unsigned int*)(unsigned int)(uintptr_t)l,
      16, 0, 0);
}
#else
__device__ inline void load_lds16(const void* g, void* l) {
  const int lane = threadIdx.x & 63;
  *(uint4*)((char*)l + lane * 16) = *(const uint4*)g;
}
#endif

__device__ inline float wave_reduce_sum(float v) {
#pragma unroll
  for (int off = 32; off > 0; off >>= 1) v += __shfl_down(v, off, 64);
  return v;
}

// ---------------- fused weight convert + permute (one launch) --------------
// Live-gate packing: permuted row r in [0,2048): gate=(r>>4)&3,
// n=((r>>6)<<4)+(r&15) in [0,512). orig = gate*1024 + n.
__global__ __launch_bounds__(256) void convert_all_kernel(
    const float* __restrict__ w_ih, const float* __restrict__ w_hh,
    const float* __restrict__ p1_w, const float* __restrict__ p2_w,
    const float* __restrict__ gcn_w, const float* __restrict__ b_ih,
    const float* __restrict__ b_hh, unsigned short* __restrict__ wihb,
    unsigned short* __restrict__ whhb, unsigned short* __restrict__ p1b,
    unsigned short* __restrict__ p2b, unsigned short* __restrict__ gcnb,
    float* __restrict__ bcomb) {
  const int p = blockIdx.x * 256 + threadIdx.x;
  if (p < 262144) {
    const int e = p * 4, r = e >> 9, c = e & 511;
    const int orig = ((r >> 4) & 3) * 1024 + ((r >> 6) << 4) + (r & 15);
    float4 v = *(const float4*)(w_ih + (size_t)orig * 512 + c);
    *(ushort4*)(wihb + (size_t)r * 512 + c) =
        make_ushort4(f2bf(v.x), f2bf(v.y), f2bf(v.z), f2bf(v.w));
  } else if (p < 524288) {
    const int e = (p - 262144) * 4, r = e >> 9, c = e & 511;
    const int orig = ((r >> 4) & 3) * 1024 + ((r >> 6) << 4) + (r & 15);
    float4 v = *(const float4*)(w_hh + (size_t)orig * 1024 + c);
    *(ushort4*)(whhb + (size_t)r * 512 + c) =
        make_ushort4(f2bf(v.x), f2bf(v.y), f2bf(v.z), f2bf(v.w));
  } else if (p < 655360) {
    const int e = (p - 524288) * 4;
    float4 v = *(const float4*)(p1_w + e);
    *(ushort4*)(p1b + e) =
        make_ushort4(f2bf(v.x), f2bf(v.y), f2bf(v.z), f2bf(v.w));
  } else if (p < 786432) {
    const int e = (p - 655360) * 4;
    float4 v = *(const float4*)(p2_w + e);
    *(ushort4*)(p2b + e) =
        make_ushort4(f2bf(v.x), f2bf(v.y), f2bf(v.z), f2bf(v.w));
  } else if (p < 819200) {
    const int e = (p - 786432) * 4;
    float4 v = *(const float4*)(gcn_w + e);
    *(ushort4*)(gcnb + e) =
        make_ushort4(f2bf(v.x), f2bf(v.y), f2bf(v.z), f2bf(v.w));
  } else if (p < 819712) {
    const int c = (p - 819200) * 4;
    const int orig = ((c >> 4) & 3) * 1024 + ((c >> 6) << 4) + (c & 15);
    float4 a = *(const float4*)(b_ih + orig);
    float4 b = *(const float4*)(b_hh + orig);
    *(float4*)(bcomb + c) =
        make_float4(a.x + b.x, a.y + b.y, a.z + b.z, a.w + b.w);
  }
}

// ---------------- neighbor encoder v5: reg-cached ent rows -----------------
__global__ __launch_bounds__(256) void neighbor_kernel(
    const int* __restrict__ query, const int* __restrict__ support,
    const int* __restrict__ qlc, const int* __restrict__ qrc,
    const int* __restrict__ slc, const int* __restrict__ src_,
    const float* __restrict__ emb, unsigned short* __restrict__ mc,
    int B, int F) {
  const int r = blockIdx.x;
  const int tid = threadIdx.x;
  const int* conn;
  int id;
  if (r < B) {
    conn = qlc + (size_t)r * 128; id = query[2 * r];
  } else if (r < 2 * B) {
    int b = r - B; conn = qrc + (size_t)b * 128; id = query[2 * b + 1];
  } else if (r < 2 * B + F) {
    int f = r - 2 * B; conn = slc + (size_t)f * 128; id = support[2 * f];
  } else {
    int f = r - 2 * B - F; conn = src_ + (size_t)f * 128; id = support[2 * f + 1];
  }

  __shared__ __align__(16) float cent[256];
  __shared__ __align__(16) float entpart[4 * 256];
  __shared__ float sims[64];
  __shared__ int rel_ids[64];
  __shared__ int ent_ids[64];
  __shared__ short list[32];
  __shared__ float red[4];
  __shared__ float cnorm_s;
  __shared__ unsigned long long selmask_s;

  if (tid < 64) {
    rel_ids[tid] = conn[2 * tid];
    ent_ids[tid] = conn[2 * tid + 1];
  }
  float cv = emb[(size_t)id * 256 + tid];
  cent[tid] = cv;
  float sq = wave_reduce_sum(cv * cv);
  if ((tid & 63) == 0) red[tid >> 6] = sq;
  __syncthreads();
  if (tid == 0) cnorm_s = sqrtf(red[0] + red[1] + red[2] + red[3]);
  __syncthreads();
  const float cn = cnorm_s;

  const int wave = tid >> 6, lane = tid & 63;
  const float4 cv4 = *(const float4*)(cent + lane * 4);
  uint2 ec[16];  // bf16x4-packed cache of this wave's 16 ent rows (lane slice)
#pragma unroll
  for (int t = 0; t < 16; ++t) {
    const int n = wave + 4 * t;
    const float* er = emb + (size_t)ent_ids[n] * 256;
    float4 e = *(const float4*)(er + lane * 4);
    ec[t].x = (unsigned)f2bf(e.x) | ((unsigned)f2bf(e.y) << 16);
    ec[t].y = (unsigned)f2bf(e.z) | ((unsigned)f2bf(e.w) << 16);
    float d = e.x * cv4.x + e.y * cv4.y + e.z * cv4.z + e.w * cv4.w;
    float s2 = e.x * e.x + e.y * e.y + e.z * e.z + e.w * e.w;
#pragma unroll
    for (int off = 32; off > 0; off >>= 1) {
      d += __shfl_down(d, off, 64);
      s2 += __shfl_down(s2, off, 64);
    }
    if (lane == 0) sims[n] = d / fmaxf(cn * sqrtf(s2), 1e-8f);
  }
  __syncthreads();

  // top-K=32, stable tie-break (lower index first) == lax.top_k (wave 0 only)
  if (wave == 0) {
    float my = sims[lane];
    int rank = 0;
#pragma unroll 8
    for (int j = 0; j < 64; ++j) {
      float sj = sims[j];
      rank += (sj > my) || (sj == my && j < lane);
    }
    if (rank < 32) list[rank] = (short)lane;
    unsigned long long m = __ballot(rank < 32);
    if (lane == 0) selmask_s = m;
  }
  __syncthreads();

  // selected-ent partial sums from register cache
  const unsigned long long selm = selmask_s;
  float4 pa = make_float4(0.f, 0.f, 0.f, 0.f);
#pragma unroll
  for (int t = 0; t < 16; ++t) {
    const int n = wave + 4 * t;
    if ((selm >> n) & 1ull) {
      pa.x += bf2f((unsigned short)(ec[t].x & 0xffff));
      pa.y += bf2f((unsigned short)(ec[t].x >> 16));
      pa.z += bf2f((unsigned short)(ec[t].y & 0xffff));
      pa.w += bf2f((unsigned short)(ec[t].y >> 16));
    }
  }
  *(float4*)&entpart[wave * 256 + lane * 4] = pa;
  __syncthreads();

  // rel gather (selected 32 rows) + combine ent partials
  float accR = 0.f;
#pragma unroll 2
  for (int k = 0; k < 32; k += 4) {
    const int n0 = list[k], n1 = list[k + 1], n2 = list[k + 2], n3 = list[k + 3];
    const float* p0 = emb + (size_t)rel_ids[n0] * 256;
    const float* p1 = emb + (size_t)rel_ids[n1] * 256;
    const float* p2 = emb + (size_t)rel_ids[n2] * 256;
    const float* p3 = emb + (size_t)rel_ids[n3] * 256;
    accR += (p0[tid] + p1[tid]) + (p2[tid] + p3[tid]);
  }
  const float accE = entpart[tid] + entpart[256 + tid] + entpart[512 + tid] +
                     entpart[768 + tid];
  mc[(size_t)r * 512 + tid] = f2bf(accR * (1.f / 32.f));
  mc[(size_t)r * 512 + 256 + tid] = f2bf(accE * (1.f / 32.f));
}

// ------------- LSTM step GEMM 64x64 + fused cell, double-buffered LDS ------
// grid (2048/64, B/64); 256 threads; wave w covers rows [w*16,+16) x all 64
// cols of the block -> each lane sees all 4 gates (j = gate) of index n.
// A: (B x 512 bf16) qgb or hb. Bw: (2048 x 512 bf16) permuted weights.
// mode 1: cold = 0, base written. mode 2: base read (addmat).
__global__ __launch_bounds__(256, 4) void lstm_step_kernel(
    const unsigned short* __restrict__ A,
    const unsigned short* __restrict__ Bw,
    float* __restrict__ base, const float* __restrict__ addvec,
    const float* __restrict__ qg, float* __restrict__ cbuf,
    unsigned short* __restrict__ hbf, float* __restrict__ hout, int mode) {
  __shared__ __align__(16) unsigned short As[2][64 * 32];
  __shared__ __align__(16) unsigned short Bs[2][64 * 32];
  const int tid = threadIdx.x;
  const int wid = tid >> 6, lane = tid & 63;
  const int quad = lane >> 4, l16 = lane & 15;
  const int row0 = blockIdx.y * 64, col0 = blockIdx.x * 64;

  // staging: waves 0,1 -> A rows [0,32)/[32,64); waves 2,3 -> B likewise.
  // two 16-row global_load_lds(16) per wave per K-step.
  const int half = wid >> 1;       // 0=A 1=B
  const int grp = (wid & 1) * 32;
  const int rl = lane >> 2;
  const int q = (lane & 3) ^ ((lane >> 3) & 3);  // XOR-swizzled quarter
  const unsigned short* src = half ? Bw : A;
  const int r0s = half ? col0 : row0;
  const unsigned short* P0 = src + (size_t)(r0s + grp + rl) * 512 + q * 8;
  const unsigned short* P1 = P0 + (size_t)16 * 512;
  const int lofs = grp * 32;  // within-buffer element offset

  // frag reads: A row = wid*16 + l16; B row(col) = j*16 + l16
  const int pq = quad ^ ((l16 >> 1) & 3);
  const int fAo = (wid * 16 + l16) * 32 + pq * 8;
  const int fBo = l16 * 32 + pq * 8;

  floatx4 acc[4];
#pragma unroll
  for (int j = 0; j < 4; ++j) {
    floatx4 z = {0.f, 0.f, 0.f, 0.f};
    acc[j] = z;
  }

  // prologue: stage K-tile 0 into buffer 0
  {
    unsigned short* L = (half ? Bs[0] : As[0]) + lofs;
    load_lds16(P0, L);
    load_lds16(P1, L + 16 * 32);
    P0 += 32; P1 += 32;
  }
  __syncthreads();

  int cur = 0;
  for (int k0 = 0; k0 < 512; k0 += 32) {
    if (k0 + 32 < 512) {  // prefetch next K-tile into the other buffer
      unsigned short* L = (half ? Bs[cur ^ 1] : As[cur ^ 1]) + lofs;
      load_lds16(P0, L);
      load_lds16(P1, L + 16 * 32);
      P0 += 32; P1 += 32;
    }
    const short8 af = *(const short8*)(&As[cur][0] + fAo);
    short8 bfr[4];
#pragma unroll
    for (int j = 0; j < 4; ++j)
      bfr[j] = *(const short8*)(&Bs[cur][0] + fBo + j * 16 * 32);
#pragma unroll
    for (int j = 0; j < 4; ++j)
      acc[j] = __builtin_amdgcn_mfma_f32_16x16x32_bf16(af, bfr[j], acc[j],
                                                       0, 0, 0);
    __syncthreads();  // implicit vmcnt(0): prefetch landed; reads of cur done
    cur ^= 1;
  }

  // epilogue: cell math; lane holds 4 rows x 4 gates
  const int n = ((col0 >> 6) << 4) + l16;  // gate index in [0,512)
  float av[4];
#pragma unroll
  for (int j = 0; j < 4; ++j) av[j] = addvec[col0 + j * 16 + l16];
#pragma unroll
  for (int r = 0; r < 4; ++r) {
    const int row = row0 + wid * 16 + quad * 4 + r;
    float v[4];
#pragma unroll
    for (int j = 0; j < 4; ++j) v[j] = acc[j][r] + av[j];
    if (mode == 2) {
#pragma unroll
      for (int j = 0; j < 4; ++j)
        v[j] += base[(size_t)row * 2048 + col0 + j * 16 + l16];
    } else {
#pragma unroll
      for (int j = 0; j < 4; ++j)
        base[(size_t)row * 2048 + col0 + j * 16 + l16] = v[j];
    }
    const float cold = (mode == 1) ? 0.f : cbuf[(size_t)row * 512 + n];
    const float cn = sigm_f(v[1]) * cold + sigm_f(v[0]) * tanh_f(v[2]);
    cbuf[(size_t)row * 512 + n] = cn;
    const float hv = qg[(size_t)row * 512 + n] + sigm_f(v[3]) * tanh_f(cn);
    if (hbf) hbf[(size_t)row * 512 + n] = f2bf(hv);
    if (hout) hout[(size_t)row * 512 + n] = hv;
  }
}

// ------------- bf16 MFMA GEMM_NT 64x64, global_load_lds staging ------------
// N % 64 == 0, K % 32 == 0, M arbitrary (A rows clamped; writes guarded).
// snptr != null => GCN remap epilogue (scatter rows to qn/qnb/sn).
__global__ __launch_bounds__(256) void gemm64_kernel(
    const unsigned short* __restrict__ A, int lda,
    const unsigned short* __restrict__ Bm, int ldb,
    float* __restrict__ C, unsigned short* __restrict__ Cbf,
    int M, int N, int K,
    const float* __restrict__ bias1, const float* __restrict__ bias2,
    const float* __restrict__ addmat, int act, int rB, int rF,
    float* __restrict__ snptr) {
  __shared__ __align__(16) unsigned short As[64 * 32];
  __shared__ __align__(16) unsigned short Bs[64 * 32];
  const int tid = threadIdx.x;
  const int wid = tid >> 6, lane = tid & 63;
  const int quad = lane >> 4, l16 = lane & 15;
  const int wr = (wid >> 1) * 32, wc = (wid & 1) * 32;
  const int row0 = blockIdx.y * 64, col0 = blockIdx.x * 64;

  // staging: waves 0,1 -> A rows [0,32)/[32,64); waves 2,3 -> B likewise
  const int half = wid >> 1;       // 0=A 1=B
  const int grp = (wid & 1) * 32;
  const int rl = lane >> 2;
  const int q = (lane & 3) ^ ((lane >> 3) & 3);
  const unsigned short* src = half ? Bm : A;
  const int lds = half ? ldb : lda;
  const int r0s = half ? col0 : row0;
  int rg0 = r0s + grp + rl;
  int rg1 = rg0 + 16;
  if (!half) {  // clamp A rows (data valid; epilogue guards writes)
    rg0 = min(rg0, M - 1);
    rg1 = min(rg1, M - 1);
  }
  const unsigned short* P0 = src + (size_t)rg0 * lds + q * 8;
  const unsigned short* P1 = src + (size_t)rg1 * lds + q * 8;
  unsigned short* L0 = (half ? Bs : As) + grp * 32;
  unsigned short* L1 = L0 + 16 * 32;

  const int pq = quad ^ ((l16 >> 1) & 3);
  const unsigned short* fA = &As[(wr + l16) * 32 + pq * 8];
  const unsigned short* fB = &Bs[(wc + l16) * 32 + pq * 8];

  floatx4 acc[2][2];
#pragma unroll
  for (int i = 0; i < 2; ++i)
#pragma unroll
    for (int j = 0; j < 2; ++j) {
      floatx4 z = {0.f, 0.f, 0.f, 0.f};
      acc[i][j] = z;
    }

  for (int k0 = 0; k0 < K; k0 += 32) {
    load_lds16(P0, L0);
    load_lds16(P1, L1);
    P0 += 32; P1 += 32;
    __syncthreads();

    short8 af[2], bfr[2];
#pragma unroll
    for (int i = 0; i < 2; ++i) af[i] = *(const short8*)(fA + i * 16 * 32);
#pragma unroll
    for (int j = 0; j < 2; ++j) bfr[j] = *(const short8*)(fB + j * 16 * 32);
#pragma unroll
    for (int i = 0; i < 2; ++i)
#pragma unroll
      for (int j = 0; j < 2; ++j)
        acc[i][j] = __builtin_amdgcn_mfma_f32_16x16x32_bf16(af[i], bfr[j],
                                                            acc[i][j], 0, 0, 0);
    __syncthreads();
  }

#pragma unroll
  for (int i = 0; i < 2; ++i) {
#pragma unroll
    for (int r = 0; r < 4; ++r) {
      const int row = row0 + wr + i * 16 + quad * 4 + r;
      if (row >= M) continue;
#pragma unroll
      for (int j = 0; j < 2; ++j) {
        const int col = col0 + wc + j * 16 + l16;
        float v = acc[i][j][r];
        if (bias1) v += bias1[col];
        if (bias2) v += bias2[col];
        if (addmat) v += addmat[(size_t)row * N + col];
        if (act == 1) v = tanh_f(v);
        else if (act == 2) v = fmaxf(v, 0.f);
        if (snptr) {  // GCN remap: row -> {qn | qn+256 | sn | sn+256}
          if (row < rB) {
            C[(size_t)row * 512 + col] = v;
            Cbf[(size_t)row * 512 + col] = f2bf(v);
          } else if (row < 2 * rB) {
            C[(size_t)(row - rB) * 512 + 256 + col] = v;
            Cbf[(size_t)(row - rB) * 512 + 256 + col] = f2bf(v);
          } else if (row < 2 * rB + rF) {
            snptr[(size_t)(row - 2 * rB) * 512 + col] = v;
          } else {
            snptr[(size_t)(row - 2 * rB - rF) * 512 + 256 + col] = v;
          }
        } else {
          if (C) C[(size_t)row * N + col] = v;
          if (Cbf) Cbf[(size_t)row * N + col] = f2bf(v);
        }
      }
    }
  }
}

// ------------- fp32 GEMM_NT (tiny M=F support path) ------------------------
__global__ __launch_bounds__(256) void gemm_nt_kernel(
    const float* __restrict__ A, int lda, const float* __restrict__ B, int ldb,
    float* __restrict__ C, int M, int N, int K,
    const float* __restrict__ bias1, const float* __restrict__ bias2,
    const float* __restrict__ addmat, int act) {
  __shared__ float As[16][65];
  __shared__ float Bs[16][65];
  const int tid = threadIdx.x;
  const int col0 = blockIdx.x * 64;
  const int row0 = blockIdx.y * 64;
  const int tx = tid & 15, ty = tid >> 4;
  const int lr = tid >> 2, lk = (tid & 3) << 2;

  float acc[4][4];
#pragma unroll
  for (int i = 0; i < 4; ++i)
#pragma unroll
    for (int j = 0; j < 4; ++j) acc[i][j] = 0.f;

  const int ar = row0 + lr;
  const bool avalid = ar < M;
  const float* Aptr = A + (size_t)ar * lda + lk;
  const float* Bptr = B + (size_t)(col0 + lr) * ldb + lk;

  for (int k0 = 0; k0 < K; k0 += 16) {
    float4 av = make_float4(0.f, 0.f, 0.f, 0.f);
    if (avalid) av = *(const float4*)(Aptr + k0);
    float4 bv = *(const float4*)(Bptr + k0);
    As[lk + 0][lr] = av.x; As[lk + 1][lr] = av.y;
    As[lk + 2][lr] = av.z; As[lk + 3][lr] = av.w;
    Bs[lk + 0][lr] = bv.x; Bs[lk + 1][lr] = bv.y;
    Bs[lk + 2][lr] = bv.z; Bs[lk + 3][lr] = bv.w;
    __syncthreads();
#pragma unroll
    for (int k = 0; k < 16; ++k) {
      float a0 = As[k][ty * 4 + 0], a1 = As[k][ty * 4 + 1];
      float a2 = As[k][ty * 4 + 2], a3 = As[k][ty * 4 + 3];
      float b0 = Bs[k][tx * 4 + 0], b1 = Bs[k][tx * 4 + 1];
      float b2 = Bs[k][tx * 4 + 2], b3 = Bs[k][tx * 4 + 3];
      acc[0][0] += a0 * b0; acc[0][1] += a0 * b1; acc[0][2] += a0 * b2; acc[0][3] += a0 * b3;
      acc[1][0] += a1 * b0; acc[1][1] += a1 * b1; acc[1][2] += a1 * b2; acc[1][3] += a1 * b3;
      acc[2][0] += a2 * b0; acc[2][1] += a2 * b1; acc[2][2] += a2 * b2; acc[2][3] += a2 * b3;
      acc[3][0] += a3 * b0; acc[3][1] += a3 * b1; acc[3][2] += a3 * b2; acc[3][3] += a3 * b3;
    }
    __syncthreads();
  }

#pragma unroll
  for (int i = 0; i < 4; ++i) {
    const int r = row0 + ty * 4 + i;
    if (r >= M) continue;
#pragma unroll
    for (int j = 0; j < 4; ++j) {
      const int c = col0 + tx * 4 + j;
      float v = acc[i][j];
      if (bias1) v += bias1[c];
      if (bias2) v += bias2[c];
      if (addmat) v += addmat[(size_t)r * N + c];
      if (act == 1) v = tanhf(v);
      else if (act == 2) v = fmaxf(v, 0.f);
      C[(size_t)r * N + c] = v;
    }
  }
}

// ------------- LayerNorm rows of 512; optional bf16 copy (queries) ---------
__global__ __launch_bounds__(256) void ln_kernel(
    const float* __restrict__ X, float* __restrict__ Y,
    unsigned short* __restrict__ Ybf,
    const float* __restrict__ g, const float* __restrict__ bta) {
  const int r = blockIdx.x;
  const int tid = threadIdx.x;
  const float* x = X + (size_t)r * 512;
  float x0 = x[tid], x1 = x[tid + 256];
  __shared__ float red[4];
  float s = wave_reduce_sum(x0 + x1);
  if ((tid & 63) == 0) red[tid >> 6] = s;
  __syncthreads();
  const float mean = (red[0] + red[1] + red[2] + red[3]) * (1.f / 512.f);
  __syncthreads();
  const float d0 = x0 - mean, d1 = x1 - mean;
  float v = wave_reduce_sum(d0 * d0 + d1 * d1);
  if ((tid & 63) == 0) red[tid >> 6] = v;
  __syncthreads();
  const float var = (red[0] + red[1] + red[2] + red[3]) * (1.f / 512.f);
  const float inv = 1.f / sqrtf(var + 1e-5f);
  const float y0 = d0 * inv * g[tid] + bta[tid];
  const float y1 = d1 * inv * g[tid + 256] + bta[tid + 256];
  float* y = Y + (size_t)r * 512;
  y[tid] = y0;
  y[tid + 256] = y1;
  if (Ybf) {
    Ybf[(size_t)r * 512 + tid] = f2bf(y0);
    Ybf[(size_t)r * 512 + tid + 256] = f2bf(y1);
  }
}

// ------------- support LN (F rows) + mean -> sg, single block --------------
__global__ __launch_bounds__(256) void lns_kernel(
    const float* __restrict__ X, const float* __restrict__ g,
    const float* __restrict__ bta, float* __restrict__ sg, int F) {
  const int tid = threadIdx.x;
  __shared__ float red[4];
  float a0 = 0.f, a1 = 0.f;
  for (int f = 0; f < F; ++f) {
    const float* x = X + (size_t)f * 512;
    const float x0 = x[tid], x1 = x[tid + 256];
    float s = wave_reduce_sum(x0 + x1);
    if ((tid & 63) == 0) red[tid >> 6] = s;
    __syncthreads();
    const float mean = (red[0] + red[1] + red[2] + red[3]) * (1.f / 512.f);
    __syncthreads();
    const float d0 = x0 - mean, d1 = x1 - mean;
    float v = wave_reduce_sum(d0 * d0 + d1 * d1);
    if ((tid & 63) == 0) red[tid >> 6] = v;
    __syncthreads();
    const float var = (red[0] + red[1] + red[2] + red[3]) * (1.f / 512.f);
    const float inv = 1.f / sqrtf(var + 1e-5f);
    a0 += d0 * inv * g[tid] + bta[tid];
    a1 += d1 * inv * g[tid + 256] + bta[tid + 256];
    __syncthreads();
  }
  sg[tid] = a0 / (float)F;
  sg[tid + 256] = a1 / (float)F;
}

// ------------- cvec[jp] = sum_d sg[d] * w_hh[orig(jp), 512+d] (permuted) ---
// live gates only: jp in [0,2048)
__global__ __launch_bounds__(256) void cvec_kernel(
    const float* __restrict__ whh, const float* __restrict__ sg,
    float* __restrict__ cv) {
  const int wave = threadIdx.x >> 6, lane = threadIdx.x & 63;
  const int jp = blockIdx.x * 4 + wave;
  const int orig = ((jp >> 4) & 3) * 1024 + ((jp >> 6) << 4) + (jp & 15);
  const float* wr = whh + (size_t)orig * 1024 + 512;
  float s = 0.f;
#pragma unroll
  for (int d = lane; d < 512; d += 64) s += wr[d] * sg[d];
  s = wave_reduce_sum(s);
  if (lane == 0) cv[jp] = s;
}

// ------------- out[b] = cosine(h[b], sg) -----------------------------------
__global__ __launch_bounds__(256) void final_kernel(
    const float* __restrict__ h, const float* __restrict__ sg,
    float* __restrict__ out) {
  const int b = blockIdx.x, tid = threadIdx.x;
  const float* hr = h + (size_t)b * 512;
  const float h0 = hr[tid], h1 = hr[tid + 256];
  const float s0 = sg[tid], s1 = sg[tid + 256];
  float d = h0 * s0 + h1 * s1;
  float hh = h0 * h0 + h1 * h1;
  float ssq = s0 * s0 + s1 * s1;
  __shared__ float red[3][4];
  d = wave_reduce_sum(d);
  hh = wave_reduce_sum(hh);
  ssq = wave_reduce_sum(ssq);
  if ((tid & 63) == 0) {
    red[0][tid >> 6] = d; red[1][tid >> 6] = hh; red[2][tid >> 6] = ssq;
  }
  __syncthreads();
  if (tid == 0) {
    const float D = red[0][0] + red[0][1] + red[0][2] + red[0][3];
    const float H = red[1][0] + red[1][1] + red[1][2] + red[1][3];
    const float S = red[2][0] + red[2][1] + red[2][2] + red[2][3];
    out[b] = D / (fmaxf(sqrtf(H), 1e-12f) * fmaxf(sqrtf(S), 1e-12f));
  }
}

extern "C" void kernel_launch(void* const* d_in, const int* in_sizes, int n_in,
                              void* d_out, int out_size, void* d_ws, size_t ws_size,
                              hipStream_t stream) {
  const int* query = (const int*)d_in[0];
  const int* support = (const int*)d_in[1];
  const int* qlc = (const int*)d_in[2];
  const int* qrc = (const int*)d_in[4];
  const int* slc = (const int*)d_in[6];
  const int* src_ = (const int*)d_in[8];
  const float* emb = (const float*)d_in[10];
  const float* gcn_w = (const float*)d_in[11];
  const float* gcn_wb = (const float*)d_in[12];
  const float* gcn_b = (const float*)d_in[13];
  const float* p1_w = (const float*)d_in[14];
  const float* p1_b = (const float*)d_in[15];
  const float* p2_w = (const float*)d_in[16];
  const float* p2_b = (const float*)d_in[17];
  const float* ln_g = (const float*)d_in[18];
  const float* ln_b = (const float*)d_in[19];
  const float* w_ih = (const float*)d_in[20];
  const float* w_hh = (const float*)d_in[21];
  const float* b_ih = (const float*)d_in[22];
  const float* b_hh = (const float*)d_in[23];
  float* out = (float*)d_out;

  const int B = in_sizes[0] / 2;   // 2048
  const int F = in_sizes[1] / 2;   // 5
  const int NR = 2 * B + 2 * F;    // 4106

  char* Wb = (char*)d_ws;
  size_t off = 0;
  auto alloc = [&](size_t bytes) {
    size_t o = off;
    off += (bytes + 255) & ~(size_t)255;
    return o;
  };
  const size_t base_o = alloc((size_t)B * 2048 * 4);
  const size_t mc_o   = alloc((size_t)NR * 512 * 2);
  const size_t qn_o   = alloc((size_t)B * 512 * 4);
  const size_t qnb_o  = alloc((size_t)B * 512 * 2);
  const size_t hqb_o  = alloc((size_t)B * 1024 * 2);
  const size_t oq_o   = alloc((size_t)B * 512 * 4);
  const size_t qg_o   = alloc((size_t)B * 512 * 4);
  const size_t qgb_o  = alloc((size_t)B * 512 * 2);
  const size_t cbuf_o = alloc((size_t)B * 512 * 4);
  const size_t h_o    = alloc((size_t)B * 512 * 4);
  const size_t hb0_o  = alloc((size_t)B * 512 * 2);
  const size_t hb1_o  = alloc((size_t)B * 512 * 2);
  const size_t wihb_o = alloc((size_t)2048 * 512 * 2);
  const size_t whhb_o = alloc((size_t)2048 * 512 * 2);
  const size_t p1b_o  = alloc((size_t)1024 * 512 * 2);
  const size_t p2b_o  = alloc((size_t)512 * 1024 * 2);
  const size_t gcnb_o = alloc((size_t)256 * 512 * 2);
  const size_t bcomb_o= alloc(2048 * 4);
  const size_t sn_o   = alloc((size_t)F * 512 * 4);
  const size_t hs_o   = alloc((size_t)F * 1024 * 4);
  const size_t oss_o  = alloc((size_t)F * 512 * 4);
  const size_t sg_o   = alloc(512 * 4);
  const size_t cvec_o = alloc(2048 * 4);

  auto F32 = [&](size_t o) { return (float*)(Wb + o); };
  auto BF = [&](size_t o) { return (unsigned short*)(Wb + o); };

  // 0. weight converts + gate permutation (live gates only) + combined bias
  convert_all_kernel<<<3202, 256, 0, stream>>>(
      w_ih, w_hh, p1_w, p2_w, gcn_w, b_ih, b_hh, BF(wihb_o), BF(whhb_o),
      BF(p1b_o), BF(p2b_o), BF(gcnb_o), F32(bcomb_o));

  // 1. neighbor encoder -> mc (NR x 512, bf16)
  neighbor_kernel<<<NR, 256, 0, stream>>>(query, support, qlc, qrc, slc, src_,
                                          emb, BF(mc_o), B, F);
  // 2. GCN + remap fused
  {
    dim3 g(256 / 64, (NR + 63) / 64);
    gemm64_kernel<<<g, 256, 0, stream>>>(BF(mc_o), 512, BF(gcnb_o), 512,
                                         F32(qn_o), BF(qnb_o), NR, 256, 512,
                                         gcn_wb, gcn_b, nullptr, 1, B, F,
                                         F32(sn_o));
  }
  // 3-4. support_encoder(queries)
  {
    dim3 g(1024 / 64, B / 64);
    gemm64_kernel<<<g, 256, 0, stream>>>(BF(qnb_o), 512, BF(p1b_o), 512,
                                         nullptr, BF(hqb_o), B, 1024, 512,
                                         p1_b, nullptr, nullptr, 2, 0, 0,
                                         nullptr);
  }
  {
    dim3 g(512 / 64, B / 64);
    gemm64_kernel<<<g, 256, 0, stream>>>(BF(hqb_o), 1024, BF(p2b_o), 1024,
                                         F32(oq_o), nullptr, B, 512, 1024,
                                         p2_b, nullptr, F32(qn_o), 0, 0, 0,
                                         nullptr);
  }
  // 5-6. support_encoder(supports): fp32 (M=5)
  {
    dim3 g(1024 / 64, 1);
    gemm_nt_kernel<<<g, 256, 0, stream>>>(F32(sn_o), 512, p1_w, 512, F32(hs_o),
                                          F, 1024, 512, p1_b, nullptr, nullptr,
                                          2);
  }
  {
    dim3 g(512 / 64, 1);
    gemm_nt_kernel<<<g, 256, 0, stream>>>(F32(hs_o), 1024, p2_w, 1024,
                                          F32(oss_o), F, 512, 1024, p2_b,
                                          nullptr, F32(sn_o), 0);
  }
  // 7. support LN + mean -> sg (one block)
  lns_kernel<<<1, 256, 0, stream>>>(F32(oss_o), ln_g, ln_b, F32(sg_o), F);
  // 8. LN queries -> qg f32 + bf16
  ln_kernel<<<B, 256, 0, stream>>>(F32(oq_o), F32(qg_o), BF(qgb_o), ln_g, ln_b);
  // 9. cvec (gate-permuted, live gates only)
  cvec_kernel<<<512, 256, 0, stream>>>(w_hh, F32(sg_o), F32(cvec_o));
  // 10-13. LSTM: base+step0, then steps 1..3 (64x64 tiles, 4 blocks/CU)
  {
    dim3 g(2048 / 64, B / 64);  // (32, 32)
    lstm_step_kernel<<<g, 256, 0, stream>>>(
        BF(qgb_o), BF(wihb_o), F32(base_o), F32(bcomb_o), F32(qg_o),
        F32(cbuf_o), BF(hb0_o), nullptr, 1);
    lstm_step_kernel<<<g, 256, 0, stream>>>(
        BF(hb0_o), BF(whhb_o), F32(base_o), F32(cvec_o), F32(qg_o),
        F32(cbuf_o), BF(hb1_o), nullptr, 2);
    lstm_step_kernel<<<g, 256, 0, stream>>>(
        BF(hb1_o), BF(whhb_o), F32(base_o), F32(cvec_o), F32(qg_o),
        F32(cbuf_o), BF(hb0_o), nullptr, 2);
    lstm_step_kernel<<<g, 256, 0, stream>>>(
        BF(hb0_o), BF(whhb_o), F32(base_o), F32(cvec_o), F32(qg_o),
        F32(cbuf_o), nullptr, F32(h_o), 2);
  }
  // 14. output
  final_kernel<<<B, 256, 0, stream>>>(F32(h_o), F32(sg_o), out);
}